// Round 13
// baseline (427.084 us; speedup 1.0000x reference)
//
#include <hip/hip_runtime.h>

// RNN: B=4096, T=512, I=15, H=64, O=1
// R12: 8-wave epilogue-split on the R9 structure (best measured: 139.6us).
//  - 512 thr/block, 256 blocks. Waves w and w+4 BOTH compute tile (w&3)'s
//    4 MFMAs (x-precompute + 2 recurrent; duplication is free, matrix pipe
//    was ~10% busy). Wave w tanh's rows 0-1, wave w+4 rows 2-3: per-wave
//    trans 6 -> 3 (issue 96 -> 48 cy), each writes one b32 of the exchange.
//  - x via prebuilt LDS frag ring (R9 scheme — R11 proved global-direct
//    costs ~260 cy/step in VMEM queue): staging rotates over 8 waves
//    (wave t&7 packs step t+8 from regs loaded 8 steps earlier).
//  - accx: x-MFMA for t+1 computed off-chain during step t.
//  - Exchange bits/addresses identical to R9/R11 (absmax 0.00390625):
//    hx[2][4][64][2] dbuf; write b32, read 4x b64; one lgkmcnt(0)+s_barrier.

#define T_STEPS 512
#define I_DIM 15
#define BPW 16
#define RING 16

typedef _Float16 half8 __attribute__((ext_vector_type(8)));
typedef float float8v __attribute__((ext_vector_type(8)));
typedef __attribute__((ext_vector_type(4))) float float4v;
typedef __attribute__((ext_vector_type(4))) unsigned int uint4v;

union H8U { half8 h; uint4v u; };

// pack two f32 -> f16 pair, RNE (staging path)
__device__ __forceinline__ unsigned pkh(float a, float b) {
    union { _Float16 h; unsigned short u; } A, B;
    A.h = (_Float16)a;
    B.h = (_Float16)b;
    return (unsigned)A.u | ((unsigned)B.u << 16);
}
// pack two f32 -> f16 pair, RTZ, single v_cvt_pkrtz_f16_f32 (critical path)
__device__ __forceinline__ unsigned pkz(float a, float b) {
    auto r = __builtin_amdgcn_cvt_pkrtz(a, b);
    unsigned u;
    __builtin_memcpy(&u, &r, 4);
    return u;
}
// 8 floats into a register vector (by value, no address escape)
__device__ __forceinline__ float8v load8(const float* p) {
    float8v r;
    __builtin_memcpy(&r, p, 32);
    return r;
}
// frag halves from row vectors: A = floats 0..7, B = floats 7..14
__device__ __forceinline__ uint4v fragA(float8v a) {
    return (uint4v){ pkh(a[0],a[1]), pkh(a[2],a[3]), pkh(a[4],a[5]), pkh(a[6],a[7]) };
}
__device__ __forceinline__ uint4v fragB(float8v b) {
    return (uint4v){ pkh(b[1],b[2]), pkh(b[3],b[4]), pkh(b[5],b[6]), pkh(b[7],0.f) };
}

__global__ __launch_bounds__(512, 1) void rnn_fused(
    const float* __restrict__ x,     // [4096][512][15]
    const float* __restrict__ W_ih,  // [64][15]
    const float* __restrict__ W_hh,  // [64][64]
    const float* __restrict__ b_ih,  // [64]
    const float* __restrict__ b_hh,  // [64]
    const float* __restrict__ fc_w,  // [1][64]
    const float* __restrict__ fc_b,  // [1]
    float* __restrict__ out)         // [4096]
{
    __shared__ uint4v   xring[RING][32];      // 8 KB x B-frag ring
    __shared__ unsigned hx[2][4][64][2];      // 4 KB h exchange (dbuf)
    __shared__ float    psum[8][16];          // head partials

    const int tid  = threadIdx.x;
    const int wave = tid >> 6;                // 0..7
    const int lane = tid & 63;
    const int q    = lane >> 4;
    const int n    = lane & 15;
    const int tile = wave & 3;                // owned j-tile
    const int half = wave >> 2;               // 0: rows 0,1 ; 1: rows 2,3
    const int b0   = blockIdx.x * BPW;
    const float K = 2.8853900817779268f;      // 2/ln2 folded into W and bias

    // ---- tile A-frags (pi-permuted, K-scaled, fp16), bias, head w ----
    half8 whf[3];
    float4v cbv;
    const int jcol = 32*(tile>>1) + 8*(n>>2) + 4*(tile&1) + (n&3);  // pi(tile,n)
    #pragma unroll
    for (int c = 0; c < 3; c++) {
        #pragma unroll
        for (int e = 0; e < 8; e++) {
            const int k = c*32 + q*8 + e;
            float w = 0.f;
            if (k < 64)      w = W_hh[jcol*64 + k] * K;
            else if (k < 79) w = W_ih[jcol*15 + (k - 64)] * K;
            whf[c][e] = (_Float16)w;                                // RNE
        }
    }
    #pragma unroll
    for (int r = 0; r < 4; r++) {
        const int jr = 32*(tile>>1) + 8*q + 4*(tile&1) + r;         // pi(tile,4q+r)
        cbv[r] = K * (b_ih[jr] + b_hh[jr]);
    }
    const int rbase = half * 2;
    const float fcw0 = fc_w[32*(tile>>1) + 8*q + 4*(tile&1) + rbase];
    const float fcw1 = fc_w[32*(tile>>1) + 8*q + 4*(tile&1) + rbase + 1];

    // ---- prologue: wave w stages ring slot w; preloads rows for step w+8 ----
    const float* xbase = x + (size_t)(b0 + n) * (T_STEPS * I_DIM);
    float8v rbA, rbB;
    if (lane < 16) {
        float8v a = load8(xbase + (size_t)wave * I_DIM);
        float8v b = load8(xbase + (size_t)wave * I_DIM + 7);
        xring[wave][n]      = fragA(a);
        xring[wave][n + 16] = fragB(b);
        rbA = load8(xbase + (size_t)(wave + 8) * I_DIM);
        rbB = load8(xbase + (size_t)(wave + 8) * I_DIM + 7);
    }
    hx[1][tile][lane][half] = 0u;             // h(-1) = 0
    asm volatile("s_waitcnt lgkmcnt(0)\n\ts_barrier" ::: "memory");

    // accx for t=0
    H8U xf0; xf0.u = xring[0][lane & 31];
    float4v accx = __builtin_amdgcn_mfma_f32_16x16x32_f16(whf[2], xf0.h, cbv, 0, 0, 0);

    float h0 = 0.f, h1 = 0.f;
    float4v acc;

    #pragma unroll 1
    for (int it = 0; it < T_STEPS / 8; ++it) {
        #pragma unroll
        for (int u = 0; u < 8; ++u) {
            const int t  = it * 8 + u;
            const int pr = (u + 1) & 1;       // parity of h(t-1) buffer
            const int wr = u & 1;             // parity to write h(t)
            // h(t-1) exchange reads + next x-frag read
            const uint2 h0a = *(const uint2*)&hx[pr][0][lane][0];
            const uint2 h0b = *(const uint2*)&hx[pr][1][lane][0];
            const uint2 h1a = *(const uint2*)&hx[pr][2][lane][0];
            const uint2 h1b = *(const uint2*)&hx[pr][3][lane][0];
            H8U xfn; xfn.u = xring[(t + 1) & (RING - 1)][lane & 31];

            // recurrent MFMAs (same per-tile order as R9/R11 => same bits)
            acc = accx;
            H8U hh0; hh0.u = (uint4v){h0a.x, h0a.y, h0b.x, h0b.y};
            acc = __builtin_amdgcn_mfma_f32_16x16x32_f16(whf[0], hh0.h, acc, 0, 0, 0);
            H8U hh1; hh1.u = (uint4v){h1a.x, h1a.y, h1b.x, h1b.y};
            acc = __builtin_amdgcn_mfma_f32_16x16x32_f16(whf[1], hh1.h, acc, 0, 0, 0);
            // accx for t+1 (off the critical chain)
            accx = __builtin_amdgcn_mfma_f32_16x16x32_f16(whf[2], xfn.h, cbv, 0, 0, 0);

            // staging: wave u packs step t+8 from regs; reloads rows t+16
            if (wave == u && lane < 16) {
                const int ps = (t + 8) & (RING - 1);
                xring[ps][n]      = fragA(rbA);
                xring[ps][n + 16] = fragB(rbB);
                int tl = t + 16; if (tl > T_STEPS - 1) tl = T_STEPS - 1;
                rbA = load8(xbase + (size_t)tl * I_DIM);
                rbB = load8(xbase + (size_t)tl * I_DIM + 7);
            }

            // epilogue HALF: rows rbase, rbase+1 (pairing identical to R11)
            const float a0 = half ? acc[2] : acc[0];
            const float a1 = half ? acc[3] : acc[1];
            const float E0 = __builtin_amdgcn_exp2f(a0) + 1.f;
            const float E1 = __builtin_amdgcn_exp2f(a1) + 1.f;
            const float R  = __builtin_amdgcn_rcpf(E0 * E1);
            const float m  = -2.f * R;
            h0 = __builtin_fmaf(E1, m, 1.f);
            h1 = __builtin_fmaf(E0, m, 1.f);
            hx[wr][tile][lane][half] = pkz(h0, h1);

            asm volatile("s_waitcnt lgkmcnt(0)\n\ts_barrier" ::: "memory");
        }
    }

    // ---- head: each wave's 2-row slice, reduce over q, then over 8 waves ----
    float s = __builtin_fmaf(h0, fcw0, h1 * fcw1);
    s += __shfl_xor(s, 16, 64);
    s += __shfl_xor(s, 32, 64);
    if (lane < 16) psum[wave][n] = s;
    __syncthreads();
    if (tid < 16)
        out[b0 + tid] = psum[0][tid] + psum[1][tid] + psum[2][tid] + psum[3][tid]
                      + psum[4][tid] + psum[5][tid] + psum[6][tid] + psum[7][tid]
                      + fc_b[0];
}

extern "C" void kernel_launch(void* const* d_in, const int* in_sizes, int n_in,
                              void* d_out, int out_size, void* d_ws, size_t ws_size,
                              hipStream_t stream) {
    const float* x    = (const float*)d_in[0];
    const float* W_ih = (const float*)d_in[1];
    const float* W_hh = (const float*)d_in[2];
    const float* b_ih = (const float*)d_in[3];
    const float* b_hh = (const float*)d_in[4];
    const float* fc_w = (const float*)d_in[5];
    const float* fc_b = (const float*)d_in[6];
    float* out = (float*)d_out;

    rnn_fused<<<4096 / BPW, 512, 0, stream>>>(x, W_ih, W_hh, b_ih, b_hh,
                                              fc_w, fc_b, out);
}

// Round 14
// 405.111 us; speedup vs baseline: 1.0542x; 1.0542x over previous
//
#include <hip/hip_runtime.h>

// RNN: B=4096, T=512, I=15, H=64, O=1
// R13: R9 (best: 139.6us) + three bit-identical scheduling edits.
//  - accx: x-MFMA for step t+1 issued during step t (C-init=bias). The
//    accumulation order x->chunk0->chunk1 is unchanged => same bits.
//  - staging split: fragA of slot t+8 staged by wave t&3, fragB by wave
//    (t+2)&3 (each lane<16) -> per-step straggler burden halved.
//  - h-exchange reads first, x-ring read last (earliest lgkmcnt release
//    for the dependent MFMAs).
//  - Topology unchanged: 4 waves, wave w owns tile jt=w (2 dependent MFMAs +
//    4 exp2 + 2 rcp paired per step), hx[2][4][64] dbuf exchange
//    (1 ds_write_b64 + 4 ds_read_b64, lane-linear, conflict-free),
//    one lgkmcnt(0)+s_barrier per step. 16-slot LDS x-frag ring.

#define T_STEPS 512
#define I_DIM 15
#define BPW 16
#define RING 16

typedef _Float16 half8 __attribute__((ext_vector_type(8)));
typedef float float8v __attribute__((ext_vector_type(8)));
typedef __attribute__((ext_vector_type(4))) float float4v;
typedef __attribute__((ext_vector_type(4))) unsigned int uint4v;

union H8U { half8 h; uint4v u; };

// pack two f32 -> f16 pair, RNE (staging path)
__device__ __forceinline__ unsigned pkh(float a, float b) {
    union { _Float16 h; unsigned short u; } A, B;
    A.h = (_Float16)a;
    B.h = (_Float16)b;
    return (unsigned)A.u | ((unsigned)B.u << 16);
}
// pack two f32 -> f16 pair, RTZ, single v_cvt_pkrtz_f16_f32 (critical path)
__device__ __forceinline__ unsigned pkz(float a, float b) {
    auto r = __builtin_amdgcn_cvt_pkrtz(a, b);
    unsigned u;
    __builtin_memcpy(&u, &r, 4);
    return u;
}
// 8 floats into a register vector (by value, no address escape)
__device__ __forceinline__ float8v load8(const float* p) {
    float8v r;
    __builtin_memcpy(&r, p, 32);
    return r;
}
// frag halves from row vectors: A = floats 0..7, B = floats 7..14
__device__ __forceinline__ uint4v fragA(float8v a) {
    return (uint4v){ pkh(a[0],a[1]), pkh(a[2],a[3]), pkh(a[4],a[5]), pkh(a[6],a[7]) };
}
__device__ __forceinline__ uint4v fragB(float8v b) {
    return (uint4v){ pkh(b[1],b[2]), pkh(b[3],b[4]), pkh(b[5],b[6]), pkh(b[7],0.f) };
}

__global__ __launch_bounds__(256, 1) void rnn_fused(
    const float* __restrict__ x,     // [4096][512][15]
    const float* __restrict__ W_ih,  // [64][15]
    const float* __restrict__ W_hh,  // [64][64]
    const float* __restrict__ b_ih,  // [64]
    const float* __restrict__ b_hh,  // [64]
    const float* __restrict__ fc_w,  // [1][64]
    const float* __restrict__ fc_b,  // [1]
    float* __restrict__ out)         // [4096]
{
    __shared__ uint4v xring[RING][32];   // 8 KB  x B-frag ring
    __shared__ uint2  hx[2][4][64];      // 4 KB  h exchange (dbuf by t&1)
    __shared__ float  psum[4][16];       // head partials

    const int tid  = threadIdx.x;
    const int wave = tid >> 6;
    const int lane = tid & 63;
    const int q = lane >> 4;
    const int n = lane & 15;
    const int b0 = blockIdx.x * BPW;
    const int jt = wave;                 // this wave's j-tile
    const float K = 2.8853900817779268f; // 2/ln2 folded into W and bias

    // ---- own-tile A-frags (pi-permuted, K-scaled, fp16), bias, head w ----
    half8 whf[3];
    float4v cbv;
    float fcwv[4];
    const int jcol = 32*(jt>>1) + 8*(n>>2) + 4*(jt&1) + (n&3);   // pi(jt, n)
    #pragma unroll
    for (int c = 0; c < 3; c++) {
        #pragma unroll
        for (int e = 0; e < 8; e++) {
            const int k = c*32 + q*8 + e;
            float w = 0.f;
            if (k < 64)      w = W_hh[jcol*64 + k] * K;
            else if (k < 79) w = W_ih[jcol*15 + (k - 64)] * K;
            whf[c][e] = (_Float16)w;                             // RNE
        }
    }
    #pragma unroll
    for (int r = 0; r < 4; r++) {
        const int jr = 32*(jt>>1) + 8*q + 4*(jt&1) + r;          // pi(jt, 4q+r)
        cbv[r]  = K * (b_ih[jr] + b_hh[jr]);
        fcwv[r] = fc_w[jr];
    }

    const float* xrow = x + (size_t)(b0 + n) * (T_STEPS * I_DIM);

    // ---- prologue: wave w stages slots {w, w+4} (both frags, lane<16);
    //      preload rbA = row(w+8) floats 0-7, rbB = row(w+10) floats 7-14.
    float8v rbA, rbB;
    if (lane < 16) {
        #pragma unroll
        for (int j = 0; j < 2; j++) {
            const int s = wave + 4*j;
            float8v a = load8(xrow + (size_t)s * I_DIM);
            float8v b = load8(xrow + (size_t)s * I_DIM + 7);
            xring[s][n]      = fragA(a);
            xring[s][n + 16] = fragB(b);
        }
        rbA = load8(xrow + (size_t)(wave + 8) * I_DIM);
        rbB = load8(xrow + (size_t)(wave + 10) * I_DIM + 7);
    }
    hx[1][wave][lane] = uint2{0u, 0u};   // h(-1) = 0 (read at t=0)

    asm volatile("s_waitcnt lgkmcnt(0)\n\ts_barrier" ::: "memory");

    // accx for t=0 (x-MFMA with bias C-init; first link of the acc chain)
    H8U xf0; xf0.u = xring[0][lane & 31];
    float4v accx = __builtin_amdgcn_mfma_f32_16x16x32_f16(whf[2], xf0.h, cbv, 0, 0, 0);

    float4v acc;
    float hfin[4];

    #pragma unroll 1
    for (int it = 0; it < T_STEPS / 4; ++it) {
        #pragma unroll
        for (int u = 0; u < 4; ++u) {
            const int t  = it * 4 + u;
            const int pr = (u + 1) & 1;
            // h(t-1) exchange reads FIRST (earliest lgkm release)
            const uint2 h0a = hx[pr][0][lane];
            const uint2 h0b = hx[pr][1][lane];
            const uint2 h1a = hx[pr][2][lane];
            const uint2 h1b = hx[pr][3][lane];
            // x-ring read LAST (only accx for t+1 depends on it)
            H8U xfn; xfn.u = xring[(t + 1) & (RING - 1)][lane & 31];

            // recurrent MFMAs (chain: accx -> chunk0 -> chunk1; same order
            // as R9's x->chunk0->chunk1 => bit-identical trajectory)
            H8U hh0; hh0.u = (uint4v){h0a.x, h0a.y, h0b.x, h0b.y};
            acc = __builtin_amdgcn_mfma_f32_16x16x32_f16(whf[0], hh0.h, accx, 0, 0, 0);
            H8U hh1; hh1.u = (uint4v){h1a.x, h1a.y, h1b.x, h1b.y};
            acc = __builtin_amdgcn_mfma_f32_16x16x32_f16(whf[1], hh1.h, acc, 0, 0, 0);
            // accx for t+1 (independent; fills the stall window)
            accx = __builtin_amdgcn_mfma_f32_16x16x32_f16(whf[2], xfn.h, cbv, 0, 0, 0);

            // staging split: fragA by wave u, fragB by wave (u+2)&3.
            // Pack VALU overlaps the h-read/MFMA latency window.
            if (wave == u && lane < 16) {
                xring[(t + 8) & (RING - 1)][n] = fragA(rbA);
                int tl = t + 12; if (tl > T_STEPS - 1) tl = T_STEPS - 1;
                rbA = load8(xrow + (size_t)tl * I_DIM);
            }
            if (wave == ((u + 2) & 3) && lane < 16) {
                xring[(t + 8) & (RING - 1)][n + 16] = fragB(rbB);
                int tl = t + 12; if (tl > T_STEPS - 1) tl = T_STEPS - 1;
                rbB = load8(xrow + (size_t)tl * I_DIM + 7);
            }

            // tanh epilogue, pairwise-shared rcp: 4 exp2 + 2 rcp
            {
                float E0 = __builtin_amdgcn_exp2f(acc[0]) + 1.f;
                float E1 = __builtin_amdgcn_exp2f(acc[1]) + 1.f;
                float R0 = __builtin_amdgcn_rcpf(E0 * E1);
                float m0 = -2.f * R0;
                hfin[0] = __builtin_fmaf(E1, m0, 1.f);
                hfin[1] = __builtin_fmaf(E0, m0, 1.f);
                float E2 = __builtin_amdgcn_exp2f(acc[2]) + 1.f;
                float E3 = __builtin_amdgcn_exp2f(acc[3]) + 1.f;
                float R2 = __builtin_amdgcn_rcpf(E2 * E3);
                float m2 = -2.f * R2;
                hfin[2] = __builtin_fmaf(E3, m2, 1.f);
                hfin[3] = __builtin_fmaf(E2, m2, 1.f);
            }
            uint2 hp; hp.x = pkz(hfin[0], hfin[1]); hp.y = pkz(hfin[2], hfin[3]);
            hx[u & 1][wave][lane] = hp;

            asm volatile("s_waitcnt lgkmcnt(0)\n\ts_barrier" ::: "memory");
        }
    }

    // ---- head: partial over own tile, reduce over q, then over waves ----
    float s = 0.f;
    #pragma unroll
    for (int r = 0; r < 4; r++) s = __builtin_fmaf(hfin[r], fcwv[r], s);
    s += __shfl_xor(s, 16, 64);
    s += __shfl_xor(s, 32, 64);
    if (lane < 16) psum[wave][n] = s;
    __syncthreads();
    if (tid < 16)
        out[b0 + tid] = psum[0][tid] + psum[1][tid] + psum[2][tid]
                      + psum[3][tid] + fc_b[0];
}

extern "C" void kernel_launch(void* const* d_in, const int* in_sizes, int n_in,
                              void* d_out, int out_size, void* d_ws, size_t ws_size,
                              hipStream_t stream) {
    const float* x    = (const float*)d_in[0];
    const float* W_ih = (const float*)d_in[1];
    const float* W_hh = (const float*)d_in[2];
    const float* b_ih = (const float*)d_in[3];
    const float* b_hh = (const float*)d_in[4];
    const float* fc_w = (const float*)d_in[5];
    const float* fc_b = (const float*)d_in[6];
    float* out = (float*)d_out;

    rnn_fused<<<4096 / BPW, 256, 0, stream>>>(x, W_ih, W_hh, b_ih, b_hh,
                                              fc_w, fc_b, out);
}